// Round 4
// baseline (349.004 us; speedup 1.0000x reference)
//
#include <hip/hip_runtime.h>

#define BB 4
#define NN 2048
#define INF 256
#define FF 64
#define HH 8
#define NEG 0.01f

// ---------------- K1: V = X @ vW + vb  (rows = B*N = 8192) ----------------
__global__ __launch_bounds__(64) void k_v(const float* __restrict__ X,
                                          const float* __restrict__ vW,
                                          const float* __restrict__ vb,
                                          float* __restrict__ V) {
    const int f = threadIdx.x;
    const int row0 = blockIdx.x * 8;
    float acc[8];
    const float bias = vb[f];
#pragma unroll
    for (int r = 0; r < 8; ++r) acc[r] = bias;

    for (int cc = 0; cc < INF; cc += 32) {
        float w[32];
#pragma unroll
        for (int k = 0; k < 32; ++k) w[k] = vW[(size_t)(cc + k) * FF + f];
#pragma unroll
        for (int r = 0; r < 8; ++r) {
            const float* xrow = X + (size_t)(row0 + r) * INF + cc;  // block-uniform -> s_load
#pragma unroll
            for (int k = 0; k < 32; ++k) acc[r] = fmaf(xrow[k], w[k], acc[r]);
        }
    }
#pragma unroll
    for (int r = 0; r < 8; ++r) V[(size_t)(row0 + r) * FF + f] = acc[r];
}

// ---------------- K2: Q,K projections (F=64 -> H=8 each) ----------------
__global__ __launch_bounds__(256) void k_qk(const float* __restrict__ V,
                                            const float* __restrict__ qW,
                                            const float* __restrict__ qb,
                                            const float* __restrict__ kW,
                                            const float* __restrict__ kb,
                                            float* __restrict__ Qt,
                                            float* __restrict__ Kt) {
    __shared__ float vl[16][FF + 1];
    __shared__ float wl[FF][16];
    const int tid = threadIdx.x;
    const int row0 = blockIdx.x * 16;
#pragma unroll
    for (int i = 0; i < 4; ++i) {
        int idx = tid + i * 256;  // 1024 floats = 16 rows x 64
        vl[idx >> 6][idx & 63] = V[(size_t)row0 * FF + idx];
    }
    {
        int idx4 = tid * 4;
#pragma unroll
        for (int u = 0; u < 4; ++u) {
            int idx = idx4 + u;  // f*16 + c
            int f_ = idx >> 4, c_ = idx & 15;
            wl[f_][c_] = (c_ < 8) ? qW[f_ * HH + c_] : kW[f_ * HH + (c_ - 8)];
        }
    }
    __syncthreads();
    const int r = tid >> 4, c = tid & 15;
    float acc = (c < 8) ? qb[c] : kb[c - 8];
#pragma unroll
    for (int f_ = 0; f_ < FF; ++f_) acc = fmaf(vl[r][f_], wl[f_][c], acc);
    const int row = row0 + r;
    const int b = row >> 11, n = row & (NN - 1);
    if (c < 8) Qt[((size_t)(b * HH + c)) * NN + n] = acc;
    else       Kt[((size_t)(b * HH + (c - 8))) * NN + n] = acc;
}

// ---------------- K3: per-(b,h) Mp = max_j max(k,0.01k), Mn = min_j min(k,0.01k) ----------------
__global__ __launch_bounds__(256) void k_m(const float* __restrict__ Kt,
                                           float* __restrict__ Mp,
                                           float* __restrict__ Mn) {
    const int bh = blockIdx.x;
    const int tid = threadIdx.x;
    float mp = -1e30f, mn = 1e30f;
    for (int j = tid; j < NN; j += 256) {
        float k = Kt[(size_t)bh * NN + j];
        mp = fmaxf(mp, fmaxf(k, NEG * k));
        mn = fminf(mn, fminf(k, NEG * k));
    }
#pragma unroll
    for (int off = 32; off; off >>= 1) {
        mp = fmaxf(mp, __shfl_down(mp, off));
        mn = fminf(mn, __shfl_down(mn, off));
    }
    __shared__ float smp[4], smn[4];
    if ((tid & 63) == 0) { smp[tid >> 6] = mp; smn[tid >> 6] = mn; }
    __syncthreads();
    if (tid == 0) {
        mp = fmaxf(fmaxf(smp[0], smp[1]), fmaxf(smp[2], smp[3]));
        mn = fminf(fminf(smn[0], smn[1]), fminf(smn[2], smn[3]));
        Mp[bh] = mp;
        Mn[bh] = mn;
    }
}

// ---------------- K4: fused exp + P@V + normalize ----------------
// grid = (B*H) * (N/MI) = 512 blocks of 256 threads (4 waves).
// Block: one (b,h), MI=128 q-rows. Per TJ=64 j-chunk:
//   phase 1: thread t computes p=exp(lrelu(q k)-m) for row (t&127),
//            j-half (t>>7)*32..+32; denominator accumulated in a register.
//   phase 2: 4x8 register tile: 32 FMA + 3 ds_read_b128 per j.
#define TJ 64
#define MI 128
__global__ __launch_bounds__(256) void k_attn(const float* __restrict__ Qt,
                                              const float* __restrict__ Kt,
                                              const float* __restrict__ V,
                                              const float* __restrict__ Mp,
                                              const float* __restrict__ Mn,
                                              float* __restrict__ out) {
    __shared__ __align__(16) float plds[TJ][MI];   // 32 KB
    __shared__ __align__(16) float vlds[TJ][FF];   // 16 KB
    __shared__ float sden[2][MI];                  // 1 KB
    const int tid = threadIdx.x;
    const int it = blockIdx.x & 15;
    const int bh = blockIdx.x >> 4;
    const int b = bh >> 3;
    const int h = bh & 7;
    const int i0 = it * MI;

    // phase-1 identity: this thread owns row (tid&127), j-half (tid>>7)
    const int prow = tid & 127;
    const int jh = tid >> 7;  // wave-uniform: waves 0,1 -> 0; waves 2,3 -> 1
    const float q = Qt[(size_t)bh * NN + i0 + prow];
    const float m = (q > 0.f) ? q * Mp[bh] : ((q < 0.f) ? q * Mn[bh] : 0.f);
    const bool pos = (q > 0.f);
    float dreg = 0.f;  // partial softmax denominator for prow over this j-half

    // phase-2 identity: 4 rows x 8 f
    const int rg = tid >> 3;  // 0..31 row group (4 rows)
    const int cg = tid & 7;   // 0..7 col group (8 f)
    float acc[4][8];
#pragma unroll
    for (int i = 0; i < 4; ++i)
#pragma unroll
        for (int k = 0; k < 8; ++k) acc[i][k] = 0.f;

    const float* Vb = V + (size_t)b * NN * FF;
    const float* Kb = Kt + (size_t)bh * NN;

    for (int j0 = 0; j0 < NN; j0 += TJ) {
        // stage V chunk (TJ*FF = 4096 floats; 4x float4 per thread, coalesced)
        {
            const float4* src = (const float4*)(Vb + (size_t)j0 * FF);
            float4* dst = (float4*)&vlds[0][0];
#pragma unroll
            for (int u = 0; u < 4; ++u) dst[tid + u * 256] = src[tid + u * 256];
        }
        // phase 1: 32 p-values for this thread's row/half (k_j wave-uniform -> s_load)
#pragma unroll 8
        for (int jj = 0; jj < 32; ++jj) {
            float k = Kb[j0 + jh * 32 + jj];
            float kap = pos ? fmaxf(k, NEG * k) : fminf(k, NEG * k);
            float p = __expf(fmaf(q, kap, -m));
            plds[jh * 32 + jj][prow] = p;
            dreg += p;
        }
        __syncthreads();
        // phase 2: 4x8 register tile accumulation (pure FMA)
#pragma unroll 4
        for (int j = 0; j < TJ; ++j) {
            float4 pa = *(const float4*)&plds[j][rg * 4];
            float4 va = *(const float4*)&vlds[j][cg * 8];
            float4 vb4 = *(const float4*)&vlds[j][cg * 8 + 4];
            float pr[4] = {pa.x, pa.y, pa.z, pa.w};
            float vr[8] = {va.x, va.y, va.z, va.w, vb4.x, vb4.y, vb4.z, vb4.w};
#pragma unroll
            for (int i = 0; i < 4; ++i)
#pragma unroll
                for (int k = 0; k < 8; ++k) acc[i][k] = fmaf(pr[i], vr[k], acc[i][k]);
        }
        __syncthreads();
    }
    // finalize denominators
    sden[jh][prow] = dreg;
    __syncthreads();
    // epilogue: normalize + store out[b][n][h][f]
#pragma unroll
    for (int i = 0; i < 4; ++i) {
        const int r = rg * 4 + i;
        const float inv = 1.0f / (sden[0][r] + sden[1][r]);
        const int n = i0 + r;
        float* op = out + (((size_t)(b * NN + n) * HH + h) * FF) + cg * 8;
        float4 o0, o1;
        o0.x = acc[i][0] * inv; o0.y = acc[i][1] * inv;
        o0.z = acc[i][2] * inv; o0.w = acc[i][3] * inv;
        o1.x = acc[i][4] * inv; o1.y = acc[i][5] * inv;
        o1.z = acc[i][6] * inv; o1.w = acc[i][7] * inv;
        *(float4*)op = o0;
        *(float4*)(op + 4) = o1;
    }
}

extern "C" void kernel_launch(void* const* d_in, const int* in_sizes, int n_in,
                              void* d_out, int out_size, void* d_ws, size_t ws_size,
                              hipStream_t stream) {
    const float* X  = (const float*)d_in[0];
    const float* vW = (const float*)d_in[1];
    const float* vb = (const float*)d_in[2];
    const float* qW = (const float*)d_in[3];
    const float* qb = (const float*)d_in[4];
    const float* kW = (const float*)d_in[5];
    const float* kb = (const float*)d_in[6];
    float* out = (float*)d_out;

    float* V  = (float*)d_ws;                    // B*N*F = 524288
    float* Qt = V + (size_t)BB * NN * FF;        // B*H*N = 65536
    float* Kt = Qt + (size_t)BB * HH * NN;       // 65536
    float* Mp = Kt + (size_t)BB * HH * NN;       // 32
    float* Mn = Mp + BB * HH;                    // 32

    k_v<<<(BB * NN) / 8, 64, 0, stream>>>(X, vW, vb, V);
    k_qk<<<(BB * NN) / 16, 256, 0, stream>>>(V, qW, qb, kW, kb, Qt, Kt);
    k_m<<<BB * HH, 256, 0, stream>>>(Kt, Mp, Mn);
    k_attn<<<BB * HH * (NN / MI), 256, 0, stream>>>(Qt, Kt, V, Mp, Mn, out);
}

// Round 5
// 273.011 us; speedup vs baseline: 1.2784x; 1.2784x over previous
//
#include <hip/hip_runtime.h>
#include <hip/hip_fp16.h>

#define BB 4
#define NN 2048
#define INF 256
#define FF 64
#define HH 8
#define NEG 0.01f
#define LOG2E 1.44269504088896340736f

typedef __attribute__((ext_vector_type(8))) _Float16 f16x8;
typedef __attribute__((ext_vector_type(16))) float f32x16;
typedef __attribute__((ext_vector_type(4))) float f32x4;

// ---------------- K1: V = X @ vW + vb -> fp16 hi/lo, TRANSPOSED Vt[b][f][n] ----------------
__global__ __launch_bounds__(64) void k_v(const float* __restrict__ X,
                                          const float* __restrict__ vW,
                                          const float* __restrict__ vb,
                                          __half* __restrict__ Vt_hi,
                                          __half* __restrict__ Vt_lo) {
    const int f = threadIdx.x;
    const int row0 = blockIdx.x * 8;
    float acc[8];
    const float bias = vb[f];
#pragma unroll
    for (int r = 0; r < 8; ++r) acc[r] = bias;
    for (int cc = 0; cc < INF; cc += 32) {
        float w[32];
#pragma unroll
        for (int k = 0; k < 32; ++k) w[k] = vW[(size_t)(cc + k) * FF + f];
#pragma unroll
        for (int r = 0; r < 8; ++r) {
            const float* xrow = X + (size_t)(row0 + r) * INF + cc;  // block-uniform
#pragma unroll
            for (int k = 0; k < 32; ++k) acc[r] = fmaf(xrow[k], w[k], acc[r]);
        }
    }
#pragma unroll
    for (int r = 0; r < 8; ++r) {
        int row = row0 + r;
        int b = row >> 11, n = row & (NN - 1);
        float v = acc[r];
        __half hi = __float2half(v);
        __half lo = __float2half(v - __half2float(hi));
        size_t idx = ((size_t)b * FF + f) * NN + n;
        Vt_hi[idx] = hi;
        Vt_lo[idx] = lo;
    }
}

// ---------------- K2: Q,K projections; Qt2 = (V qW + qb)*log2e; kapP/kapN ----------------
__global__ __launch_bounds__(256) void k_qk(const __half* __restrict__ Vt_hi,
                                            const __half* __restrict__ Vt_lo,
                                            const float* __restrict__ qW,
                                            const float* __restrict__ qb,
                                            const float* __restrict__ kW,
                                            const float* __restrict__ kb,
                                            float* __restrict__ Qt2,
                                            float* __restrict__ kapP,
                                            float* __restrict__ kapN) {
    const int b = blockIdx.x >> 3;
    const int n = (blockIdx.x & 7) * 256 + threadIdx.x;
    float qa[HH], ka[HH];
#pragma unroll
    for (int h = 0; h < HH; ++h) { qa[h] = qb[h]; ka[h] = kb[h]; }
    const __half* ph = Vt_hi + (size_t)b * FF * NN + n;
    const __half* pl = Vt_lo + (size_t)b * FF * NN + n;
#pragma unroll 8
    for (int f = 0; f < FF; ++f) {
        float v = __half2float(ph[(size_t)f * NN]) + __half2float(pl[(size_t)f * NN]);
#pragma unroll
        for (int h = 0; h < HH; ++h) {
            qa[h] = fmaf(v, qW[f * HH + h], qa[h]);
            ka[h] = fmaf(v, kW[f * HH + h], ka[h]);
        }
    }
#pragma unroll
    for (int h = 0; h < HH; ++h) {
        size_t o = ((size_t)(b * HH + h)) * NN + n;
        Qt2[o] = qa[h] * LOG2E;
        float kk = ka[h];
        kapP[o] = fmaxf(kk, NEG * kk);
        kapN[o] = fminf(kk, NEG * kk);
    }
}

// ---------------- K3: Mp = max kapP, Mn = min kapN per (b,h) ----------------
__global__ __launch_bounds__(256) void k_m(const float* __restrict__ kapP,
                                           const float* __restrict__ kapN,
                                           float* __restrict__ Mp,
                                           float* __restrict__ Mn) {
    const int bh = blockIdx.x;
    const int tid = threadIdx.x;
    float mp = -1e30f, mn = 1e30f;
    for (int j = tid; j < NN; j += 256) {
        mp = fmaxf(mp, kapP[(size_t)bh * NN + j]);
        mn = fminf(mn, kapN[(size_t)bh * NN + j]);
    }
#pragma unroll
    for (int off = 32; off; off >>= 1) {
        mp = fmaxf(mp, __shfl_down(mp, off));
        mn = fminf(mn, __shfl_down(mn, off));
    }
    __shared__ float smp[4], smn[4];
    if ((tid & 63) == 0) { smp[tid >> 6] = mp; smn[tid >> 6] = mn; }
    __syncthreads();
    if (tid == 0) {
        Mp[bh] = fmaxf(fmaxf(smp[0], smp[1]), fmaxf(smp[2], smp[3]));
        Mn[bh] = fminf(fminf(smn[0], smn[1]), fminf(smn[2], smn[3]));
    }
}

// ---------------- K4: MFMA fused exp + P@V + normalize (no LDS, no barriers) ----------------
// Per wave: one (b,h), 32 q-rows, all 64 f. A-frag (P tile) generated in-register:
// lane l -> A row l&31, k = (l>>5)*8+e. B-frag: Vt[f = ctile*32 + (l&31)][j..j+8].
// 3 products per ctile: Ah*Bh + Al*Bh + Ah*Bl  (fp32-equivalent accuracy).
__global__ __launch_bounds__(256, 2) void k_attn(const float* __restrict__ Qt2,
                                                 const float* __restrict__ kapP,
                                                 const float* __restrict__ kapN,
                                                 const float* __restrict__ Mp,
                                                 const float* __restrict__ Mn,
                                                 const __half* __restrict__ Vt_hi,
                                                 const __half* __restrict__ Vt_lo,
                                                 float* __restrict__ out) {
    const int tid = threadIdx.x;
    const int lane = tid & 63;
    const int wave = tid >> 6;
    // XCD-grouped mapping: blk%8 = XCD; each XCD owns 4 bh (single b per XCD L2)
    const int blk = blockIdx.x;
    const int idx = blk >> 3;                     // 0..63
    const int bh = (blk & 7) * 4 + (idx >> 4);    // 0..31
    const int rowtile = (idx & 15) * 4 + wave;    // 0..63
    const int b = bh >> 3, h = bh & 7;

    const int rl = lane & 31;   // A row within tile / B col within ctile
    const int kh = lane >> 5;   // k-half
    const int kofs = kh * 8;
    const int row = rowtile * 32 + rl;

    const float q2 = Qt2[(size_t)bh * NN + row];
    const float m2 = (q2 > 0.f) ? q2 * Mp[bh] : q2 * Mn[bh];  // exact row max (log2 units)
    const float* kap = ((q2 > 0.f) ? kapP : kapN) + (size_t)bh * NN;

    const f16x8* vb0h = (const f16x8*)(Vt_hi + ((size_t)b * FF + rl) * NN + kofs);
    const f16x8* vb1h = (const f16x8*)(Vt_hi + ((size_t)b * FF + 32 + rl) * NN + kofs);
    const f16x8* vb0l = (const f16x8*)(Vt_lo + ((size_t)b * FF + rl) * NN + kofs);
    const f16x8* vb1l = (const f16x8*)(Vt_lo + ((size_t)b * FF + 32 + rl) * NN + kofs);

    f32x16 acc0 = {};
    f32x16 acc1 = {};
    float den = 0.f;

#pragma unroll 2
    for (int j0 = 0; j0 < NN; j0 += 16) {
        f32x4 kA = *(const f32x4*)(kap + j0 + kofs);
        f32x4 kB = *(const f32x4*)(kap + j0 + kofs + 4);
        float p[8];
#pragma unroll
        for (int e = 0; e < 4; ++e) {
            p[e]     = __builtin_amdgcn_exp2f(fmaf(q2, kA[e], -m2));
            p[e + 4] = __builtin_amdgcn_exp2f(fmaf(q2, kB[e], -m2));
        }
        f16x8 ah, al;
#pragma unroll
        for (int e = 0; e < 8; ++e) {
            den += p[e];
            _Float16 hi = (_Float16)p[e];
            ah[e] = hi;
            al[e] = (_Float16)(p[e] - (float)hi);
        }
        f16x8 b0h = vb0h[j0 >> 3];
        f16x8 b1h = vb1h[j0 >> 3];
        f16x8 b0l = vb0l[j0 >> 3];
        f16x8 b1l = vb1l[j0 >> 3];
        acc0 = __builtin_amdgcn_mfma_f32_32x32x16_f16(ah, b0h, acc0, 0, 0, 0);
        acc1 = __builtin_amdgcn_mfma_f32_32x32x16_f16(ah, b1h, acc1, 0, 0, 0);
        acc0 = __builtin_amdgcn_mfma_f32_32x32x16_f16(al, b0h, acc0, 0, 0, 0);
        acc1 = __builtin_amdgcn_mfma_f32_32x32x16_f16(al, b1h, acc1, 0, 0, 0);
        acc0 = __builtin_amdgcn_mfma_f32_32x32x16_f16(ah, b0l, acc0, 0, 0, 0);
        acc1 = __builtin_amdgcn_mfma_f32_32x32x16_f16(ah, b1l, acc1, 0, 0, 0);
    }
    // full denominator per row (combine the two k-halves)
    den += __shfl_xor(den, 32);
    // epilogue: C layout col = lane&31, row = (reg&3) + 8*(reg>>2) + 4*(lane>>5)
    float* ob = out + (size_t)b * NN * (HH * FF) + (size_t)h * FF;
#pragma unroll
    for (int reg = 0; reg < 16; ++reg) {
        int rloc = (reg & 3) + 8 * (reg >> 2) + 4 * kh;
        float d = __shfl(den, rloc);
        float inv = 1.0f / d;
        int n = rowtile * 32 + rloc;
        float* op = ob + (size_t)n * (HH * FF);
        op[rl]      = acc0[reg] * inv;
        op[32 + rl] = acc1[reg] * inv;
    }
}

extern "C" void kernel_launch(void* const* d_in, const int* in_sizes, int n_in,
                              void* d_out, int out_size, void* d_ws, size_t ws_size,
                              hipStream_t stream) {
    const float* X  = (const float*)d_in[0];
    const float* vW = (const float*)d_in[1];
    const float* vb = (const float*)d_in[2];
    const float* qW = (const float*)d_in[3];
    const float* qb = (const float*)d_in[4];
    const float* kW = (const float*)d_in[5];
    const float* kb = (const float*)d_in[6];
    float* out = (float*)d_out;

    char* w = (char*)d_ws;
    __half* Vt_hi = (__half*)(w);                 // 1,048,576 B
    __half* Vt_lo = (__half*)(w + 1048576);       // 1,048,576 B
    float* Qt2  = (float*)(w + 2097152);          // 262,144 B
    float* kapP = (float*)(w + 2359296);          // 262,144 B
    float* kapN = (float*)(w + 2621440);          // 262,144 B
    float* Mp   = (float*)(w + 2883584);          // 128 B
    float* Mn   = (float*)(w + 2883712);          // 128 B

    k_v<<<(BB * NN) / 8, 64, 0, stream>>>(X, vW, vb, Vt_hi, Vt_lo);
    k_qk<<<BB * 8, 256, 0, stream>>>(Vt_hi, Vt_lo, qW, qb, kW, kb, Qt2, kapP, kapN);
    k_m<<<BB * HH, 256, 0, stream>>>(kapP, kapN, Mp, Mn);
    k_attn<<<BB * HH * 16, 256, 0, stream>>>(Qt2, kapP, kapN, Mp, Mn, Vt_hi, Vt_lo, out);
}

// Round 9
// 243.125 us; speedup vs baseline: 1.4355x; 1.1229x over previous
//
#include <hip/hip_runtime.h>
#include <hip/hip_fp16.h>

#define BB 4
#define NN 2048
#define INF 256
#define FF 64
#define HH 8
#define NEG 0.01f
#define LOG2E 1.44269504088896340736f

typedef __attribute__((ext_vector_type(8))) _Float16 f16x8;
typedef __attribute__((ext_vector_type(16))) float f32x16;
typedef __attribute__((ext_vector_type(4))) float f32x4;

// ---------------- K1: fused V + Q/K + kap: 256 blocks x 256 threads, 32 rows/block ----
// Phase A: V[row][f] via direct X reads (8-lane-shared) -> LDS vstage.
// Phase B: coalesced hi/lo transposed Vt writes (lane spans n).  [n is LOCAL to batch]
// Phase C: Q,K projections + kapP/kapN/Qt2 from LDS V (coalesced writes).
__global__ __launch_bounds__(256) void k_vqk(const float* __restrict__ X,
    const float* __restrict__ vW, const float* __restrict__ vb,
    const float* __restrict__ qW, const float* __restrict__ qb,
    const float* __restrict__ kW, const float* __restrict__ kb,
    __half* __restrict__ Vt_hi, __half* __restrict__ Vt_lo,
    float* __restrict__ Qt2, float* __restrict__ kapP, float* __restrict__ kapN)
{
    __shared__ float vstage[32][65];
    __shared__ float qwl[512];  // [f*8+h]
    __shared__ float kwl[512];
    const int t = threadIdx.x;
    const int n0 = blockIdx.x * 32;      // GLOBAL row base (0..8191)
    const int b = n0 >> 11;
    const int nl = n0 & (NN - 1);        // LOCAL row base within batch (bugfix r8)

    qwl[t] = qW[t]; qwl[t + 256] = qW[t + 256];
    kwl[t] = kW[t]; kwl[t + 256] = kW[t + 256];

    // Phase A: thread (row = t>>3, fq = t&7) computes V[row][fq*8..+8]
    {
        const int row = t >> 3, fq = t & 7;
        float acc[8];
        const float4 b0 = *(const float4*)(vb + fq * 8);
        const float4 b1 = *(const float4*)(vb + fq * 8 + 4);
        acc[0] = b0.x; acc[1] = b0.y; acc[2] = b0.z; acc[3] = b0.w;
        acc[4] = b1.x; acc[5] = b1.y; acc[6] = b1.z; acc[7] = b1.w;
        const float* xrow = X + (size_t)(n0 + row) * INF;   // X uses GLOBAL row
        const float4* wv = (const float4*)(vW);
#pragma unroll 4
        for (int k = 0; k < INF; ++k) {
            float x = xrow[k];
            float4 w0 = wv[k * 16 + fq * 2];
            float4 w1 = wv[k * 16 + fq * 2 + 1];
            acc[0] = fmaf(x, w0.x, acc[0]); acc[1] = fmaf(x, w0.y, acc[1]);
            acc[2] = fmaf(x, w0.z, acc[2]); acc[3] = fmaf(x, w0.w, acc[3]);
            acc[4] = fmaf(x, w1.x, acc[4]); acc[5] = fmaf(x, w1.y, acc[5]);
            acc[6] = fmaf(x, w1.z, acc[6]); acc[7] = fmaf(x, w1.w, acc[7]);
        }
#pragma unroll
        for (int e = 0; e < 8; ++e) vstage[row][fq * 8 + e] = acc[e];
    }
    __syncthreads();
    // Phase B: Vt hi/lo writes: thread (f = t>>2, ng = t&3) writes 8 n contiguous
    {
        const int f = t >> 2, ng = t & 3;
        f16x8 hbuf, lbuf;
#pragma unroll
        for (int e = 0; e < 8; ++e) {
            float v = vstage[ng * 8 + e][f];
            _Float16 hi = (_Float16)v;
            hbuf[e] = hi;
            lbuf[e] = (_Float16)(v - (float)hi);
        }
        size_t o = ((size_t)b * FF + f) * NN + nl + ng * 8;   // LOCAL n (bugfix r8)
        *(f16x8*)(Vt_hi + o) = hbuf;
        *(f16x8*)(Vt_lo + o) = lbuf;
    }
    // Phase C: Q/K: thread (r2 = t&31, h = t>>5): two dot-64
    {
        const int r2 = t & 31, h = t >> 5;
        float qa = qb[h], ka = kb[h];
#pragma unroll
        for (int f = 0; f < FF; ++f) {
            float v = vstage[r2][f];
            qa = fmaf(v, qwl[f * 8 + h], qa);
            ka = fmaf(v, kwl[f * 8 + h], ka);
        }
        size_t o = ((size_t)(b * HH + h)) * NN + nl + r2;     // LOCAL n (bugfix r8)
        Qt2[o] = qa * LOG2E;
        kapP[o] = fmaxf(ka, NEG * ka);
        kapN[o] = fminf(ka, NEG * ka);
    }
}

// ---------------- K2: Mp = max kapP, Mn = min kapN per (b,h) ----------------
__global__ __launch_bounds__(256) void k_m(const float* __restrict__ kapP,
                                           const float* __restrict__ kapN,
                                           float* __restrict__ Mp,
                                           float* __restrict__ Mn) {
    const int bh = blockIdx.x;
    const int tid = threadIdx.x;
    float mp = -1e30f, mn = 1e30f;
    for (int j = tid; j < NN; j += 256) {
        mp = fmaxf(mp, kapP[(size_t)bh * NN + j]);
        mn = fminf(mn, kapN[(size_t)bh * NN + j]);
    }
#pragma unroll
    for (int off = 32; off; off >>= 1) {
        mp = fmaxf(mp, __shfl_down(mp, off));
        mn = fminf(mn, __shfl_down(mn, off));
    }
    __shared__ float smp[4], smn[4];
    if ((tid & 63) == 0) { smp[tid >> 6] = mp; smn[tid >> 6] = mn; }
    __syncthreads();
    if (tid == 0) {
        Mp[bh] = fmaxf(fmaxf(smp[0], smp[1]), fmaxf(smp[2], smp[3]));
        Mn[bh] = fminf(fminf(smn[0], smn[1]), fminf(smn[2], smn[3]));
    }
}

// ---------------- K3: MFMA fused exp + P@V, j-split x2 + LDS combine ----------------
// 1024 blocks x 4 waves. Block: one bh, 2 row-tiles (64 rows); waves (tile, jseg):
// wave = jseg*2 + tile. Each wave: 32 rows x 1024 j, prefetch-pipelined chunks of 16 j,
// 6 MFMAs/chunk (Ah*Bh + Al*Bh + Ah*Bl for both f-halves). jseg partials combined in LDS.
__global__ __launch_bounds__(256, 4) void k_attn(const float* __restrict__ Qt2,
                                                 const float* __restrict__ kapP,
                                                 const float* __restrict__ kapN,
                                                 const float* __restrict__ Mp,
                                                 const float* __restrict__ Mn,
                                                 const __half* __restrict__ Vt_hi,
                                                 const __half* __restrict__ Vt_lo,
                                                 float* __restrict__ out) {
    __shared__ float comb[2][64][33];
    const int tid = threadIdx.x;
    const int lane = tid & 63;
    const int wave = tid >> 6;
    const int blk = blockIdx.x;
    const int xcd = blk & 7;            // XCD-grouped: 2 XCDs per b -> Vt L2-resident
    const int sub = blk >> 3;           // 0..127
    const int bh = xcd * 4 + (sub >> 5);
    const int pairidx = sub & 31;
    const int tile = wave & 1;
    const int jseg = wave >> 1;
    const int rowtile = pairidx * 2 + tile;
    const int b = bh >> 3, h = bh & 7;

    const int rl = lane & 31;   // A row / B col within tile
    const int kh = lane >> 5;   // k-half
    const int kofs = kh * 8;
    const int row = rowtile * 32 + rl;
    const int jbase = jseg * (NN / 2);

    const float q2 = Qt2[(size_t)bh * NN + row];
    const float m2 = (q2 > 0.f) ? q2 * Mp[bh] : q2 * Mn[bh];  // exact row max (log2 units)
    const float* kap = ((q2 > 0.f) ? kapP : kapN) + (size_t)bh * NN + jbase;

    const f16x8* vb0h = (const f16x8*)(Vt_hi + ((size_t)b * FF + rl) * NN + jbase + kofs);
    const f16x8* vb1h = (const f16x8*)(Vt_hi + ((size_t)b * FF + 32 + rl) * NN + jbase + kofs);
    const f16x8* vb0l = (const f16x8*)(Vt_lo + ((size_t)b * FF + rl) * NN + jbase + kofs);
    const f16x8* vb1l = (const f16x8*)(Vt_lo + ((size_t)b * FF + 32 + rl) * NN + jbase + kofs);

    f32x16 acc0 = {}, acc1 = {};
    float den = 0.f;

    // software pipeline: prefetch chunk c+1 while computing chunk c
    f16x8 cb0h = vb0h[0], cb1h = vb1h[0], cb0l = vb0l[0], cb1l = vb1l[0];
    f32x4 ckA = *(const f32x4*)(kap + kofs);
    f32x4 ckB = *(const f32x4*)(kap + kofs + 4);

#pragma unroll 2
    for (int c = 0; c < (NN / 2) / 16; ++c) {
        const int nc = c + 1;  // one-past prefetch on last iter lands in valid ws memory
        f16x8 nb0h = vb0h[nc * 2], nb1h = vb1h[nc * 2];
        f16x8 nb0l = vb0l[nc * 2], nb1l = vb1l[nc * 2];
        f32x4 nkA = *(const f32x4*)(kap + nc * 16 + kofs);
        f32x4 nkB = *(const f32x4*)(kap + nc * 16 + kofs + 4);
        float p[8];
#pragma unroll
        for (int e = 0; e < 4; ++e) {
            p[e]     = __builtin_amdgcn_exp2f(fmaf(q2, ckA[e], -m2));
            p[e + 4] = __builtin_amdgcn_exp2f(fmaf(q2, ckB[e], -m2));
        }
        f16x8 ah, al;
#pragma unroll
        for (int e = 0; e < 8; ++e) {
            den += p[e];
            _Float16 hi = (_Float16)p[e];
            ah[e] = hi;
            al[e] = (_Float16)(p[e] - (float)hi);
        }
        acc0 = __builtin_amdgcn_mfma_f32_32x32x16_f16(ah, cb0h, acc0, 0, 0, 0);
        acc1 = __builtin_amdgcn_mfma_f32_32x32x16_f16(ah, cb1h, acc1, 0, 0, 0);
        acc0 = __builtin_amdgcn_mfma_f32_32x32x16_f16(al, cb0h, acc0, 0, 0, 0);
        acc1 = __builtin_amdgcn_mfma_f32_32x32x16_f16(al, cb1h, acc1, 0, 0, 0);
        acc0 = __builtin_amdgcn_mfma_f32_32x32x16_f16(ah, cb0l, acc0, 0, 0, 0);
        acc1 = __builtin_amdgcn_mfma_f32_32x32x16_f16(ah, cb1l, acc1, 0, 0, 0);
        cb0h = nb0h; cb1h = nb1h; cb0l = nb0l; cb1l = nb1l;
        ckA = nkA; ckB = nkB;
    }

    // combine jseg partials (exact global max -> partials add linearly)
    if (jseg == 1) {
        float* cb = &comb[tile][lane][0];
#pragma unroll
        for (int e = 0; e < 16; ++e) { cb[e] = acc0[e]; cb[e + 16] = acc1[e]; }
        cb[32] = den;
    }
    __syncthreads();
    if (jseg == 0) {
        const float* cb = &comb[tile][lane][0];
#pragma unroll
        for (int e = 0; e < 16; ++e) { acc0[e] += cb[e]; acc1[e] += cb[e + 16]; }
        den += cb[32];
        den += __shfl_xor(den, 32);  // merge k-halves -> full row denominator
        // C layout: col = lane&31, row = (reg&3) + 8*(reg>>2) + 4*kh
        float* ob = out + (size_t)b * NN * (HH * FF) + (size_t)h * FF;
#pragma unroll
        for (int reg = 0; reg < 16; ++reg) {
            int rloc = (reg & 3) + 8 * (reg >> 2) + 4 * kh;
            float d = __shfl(den, rloc);
            float inv = 1.0f / d;
            int n = rowtile * 32 + rloc;
            float* op = ob + (size_t)n * (HH * FF);
            op[rl]      = acc0[reg] * inv;
            op[32 + rl] = acc1[reg] * inv;
        }
    }
}

extern "C" void kernel_launch(void* const* d_in, const int* in_sizes, int n_in,
                              void* d_out, int out_size, void* d_ws, size_t ws_size,
                              hipStream_t stream) {
    const float* X  = (const float*)d_in[0];
    const float* vW = (const float*)d_in[1];
    const float* vb = (const float*)d_in[2];
    const float* qW = (const float*)d_in[3];
    const float* qb = (const float*)d_in[4];
    const float* kW = (const float*)d_in[5];
    const float* kb = (const float*)d_in[6];
    float* out = (float*)d_out;

    char* w = (char*)d_ws;
    __half* Vt_hi = (__half*)(w);                 // 1,048,576 B
    __half* Vt_lo = (__half*)(w + 1048576);       // 1,048,576 B
    float* Qt2  = (float*)(w + 2097152);          // 262,144 B
    float* kapP = (float*)(w + 2359296);          // 262,144 B
    float* kapN = (float*)(w + 2621440);          // 262,144 B
    float* Mp   = (float*)(w + 2883584);          // 128 B
    float* Mn   = (float*)(w + 2883712);          // 128 B

    k_vqk<<<(BB * NN) / 32, 256, 0, stream>>>(X, vW, vb, qW, qb, kW, kb,
                                              Vt_hi, Vt_lo, Qt2, kapP, kapN);
    k_m<<<BB * HH, 256, 0, stream>>>(kapP, kapN, Mp, Mn);
    k_attn<<<BB * HH * 32, 256, 0, stream>>>(Qt2, kapP, kapN, Mp, Mn, Vt_hi, Vt_lo, out);
}

// Round 10
// 182.019 us; speedup vs baseline: 1.9174x; 1.3357x over previous
//
#include <hip/hip_runtime.h>
#include <hip/hip_fp16.h>

#define BB 4
#define NN 2048
#define INF 256
#define FF 64
#define HH 8
#define NEG 0.01f
#define LOG2E 1.44269504088896340736f

typedef __attribute__((ext_vector_type(8))) _Float16 f16x8;
typedef __attribute__((ext_vector_type(4))) _Float16 f16x4v;
typedef __attribute__((ext_vector_type(16))) float f32x16;
typedef __attribute__((ext_vector_type(4))) float f32x4;

// ---- K1: fused V + Vt(f16) + Q/K/kap. 512 blocks x 256 thr, 16 rows/block ----
__global__ __launch_bounds__(256) void k_vqk(const float* __restrict__ X,
    const float* __restrict__ vW, const float* __restrict__ vb,
    const float* __restrict__ qW, const float* __restrict__ qb,
    const float* __restrict__ kW, const float* __restrict__ kb,
    __half* __restrict__ Vt,
    float* __restrict__ Qt2, float* __restrict__ kapP, float* __restrict__ kapN)
{
    __shared__ float vstage[16][68];
    __shared__ float qwl[512], kwl[512];   // [f*8+h]
    const int t = threadIdx.x;
    const int n0 = blockIdx.x * 16;      // GLOBAL row base
    const int b = n0 >> 11;
    const int nl = n0 & (NN - 1);        // LOCAL row base (r8 lesson)

    qwl[t] = qW[t]; qwl[t + 256] = qW[t + 256];
    kwl[t] = kW[t]; kwl[t + 256] = kW[t + 256];

    // Phase A: thread (row = t>>4, fc = t&15) computes V[row][fc*4..+4]
    {
        const int row = t >> 4, fc = t & 15;
        float4 a = *(const float4*)(vb + fc * 4);
        float ac0 = a.x, ac1 = a.y, ac2 = a.z, ac3 = a.w;
        const float* xrow = X + (size_t)(n0 + row) * INF;
        const float* wv = vW + fc * 4;
#pragma unroll 8
        for (int k = 0; k < INF; ++k) {
            float x = xrow[k];
            float4 w = *(const float4*)(wv + k * FF);
            ac0 = fmaf(x, w.x, ac0); ac1 = fmaf(x, w.y, ac1);
            ac2 = fmaf(x, w.z, ac2); ac3 = fmaf(x, w.w, ac3);
        }
        float4 o; o.x = ac0; o.y = ac1; o.z = ac2; o.w = ac3;
        *(float4*)&vstage[row][fc * 4] = o;
    }
    __syncthreads();
    // Phase B: Vt f16 transposed write: thread (f = t>>2, nq = t&3) -> 4 n each
    {
        const int f = t >> 2, nq = t & 3;
        f16x4v hb;
#pragma unroll
        for (int e = 0; e < 4; ++e) hb[e] = (_Float16)vstage[nq * 4 + e][f];
        *(f16x4v*)(Vt + ((size_t)b * FF + f) * NN + nl + nq * 4) = hb;
    }
    // Phase C: Q/K: thread (r = t>>4, h = (t>>1)&7, half = t&1): dot-32 + pair-combine
    {
        const int r = t >> 4, h = (t >> 1) & 7, half = t & 1;
        float pq = 0.f, pk = 0.f;
        const int f0 = half * 32;
#pragma unroll
        for (int i = 0; i < 32; ++i) {
            float v = vstage[r][f0 + i];
            pq = fmaf(v, qwl[(f0 + i) * 8 + h], pq);
            pk = fmaf(v, kwl[(f0 + i) * 8 + h], pk);
        }
        float oq = __shfl_xor(pq, 1);
        float ok = __shfl_xor(pk, 1);
        if (half == 0) {
            float qa = pq + oq + qb[h];
            float ka = pk + ok + kb[h];
            size_t o = ((size_t)(b * HH + h)) * NN + nl + r;
            Qt2[o] = qa * LOG2E;
            kapP[o] = fmaxf(ka, NEG * ka);
            kapN[o] = fminf(ka, NEG * ka);
        }
    }
}

// ---- K2: partial Mp/Mn per (bh, 256-j segment): 256 blocks ----
__global__ __launch_bounds__(256) void k_m(const float* __restrict__ kapP,
                                           const float* __restrict__ kapN,
                                           float* __restrict__ Mpp,
                                           float* __restrict__ Mnp) {
    const int bh = blockIdx.x >> 3, seg = blockIdx.x & 7;
    const int tid = threadIdx.x;
    const int j = seg * 256 + tid;
    float mp = kapP[(size_t)bh * NN + j];
    float mn = kapN[(size_t)bh * NN + j];
#pragma unroll
    for (int off = 32; off; off >>= 1) {
        mp = fmaxf(mp, __shfl_down(mp, off));
        mn = fminf(mn, __shfl_down(mn, off));
    }
    __shared__ float sp[4], sn[4];
    if ((tid & 63) == 0) { sp[tid >> 6] = mp; sn[tid >> 6] = mn; }
    __syncthreads();
    if (tid == 0) {
        Mpp[blockIdx.x] = fmaxf(fmaxf(sp[0], sp[1]), fmaxf(sp[2], sp[3]));
        Mnp[blockIdx.x] = fminf(fminf(sn[0], sn[1]), fminf(sn[2], sn[3]));
    }
}

// ---- K3: MFMA fused exp + P@V. Single f16 product (threshold 5.66e-2 allows it).
// 1024 blocks x 4 waves (tile, jseg). Chunk = 32 j: 4 MFMAs, full-line V gathers.
__global__ __launch_bounds__(256, 4) void k_attn(const float* __restrict__ Qt2,
                                                 const float* __restrict__ kapP,
                                                 const float* __restrict__ kapN,
                                                 const float* __restrict__ Mpp,
                                                 const float* __restrict__ Mnp,
                                                 const __half* __restrict__ Vt,
                                                 float* __restrict__ out) {
    __shared__ float comb[2][64][33];
    const int tid = threadIdx.x;
    const int lane = tid & 63;
    const int wave = tid >> 6;
    const int blk = blockIdx.x;
    const int xcd = blk & 7;
    const int sub = blk >> 3;
    const int bh = xcd * 4 + (sub >> 5);
    const int pairidx = sub & 31;
    const int tile = wave & 1;
    const int jseg = wave >> 1;
    const int rowtile = pairidx * 2 + tile;
    const int b = bh >> 3, h = bh & 7;

    const int rl = lane & 31;
    const int kh = lane >> 5;
    const int row = rowtile * 32 + rl;
    const int jbase = jseg * (NN / 2);

    const float q2 = Qt2[(size_t)bh * NN + row];
    // fold 8 partial maxes (uniform scalar loads)
    float mp = Mpp[bh * 8], mn = Mnp[bh * 8];
#pragma unroll
    for (int s = 1; s < 8; ++s) {
        mp = fmaxf(mp, Mpp[bh * 8 + s]);
        mn = fminf(mn, Mnp[bh * 8 + s]);
    }
    const float m2 = (q2 > 0.f) ? q2 * mp : q2 * mn;  // exact row max (log2 units)
    const float* kap = ((q2 > 0.f) ? kapP : kapN) + (size_t)bh * NN + jbase + kh * 8;

    const __half* pv0 = Vt + ((size_t)b * FF + rl) * NN + jbase + kh * 8;
    const __half* pv1 = pv0 + (size_t)32 * NN;

    f32x16 acc0 = {}, acc1 = {};
    float den = 0.f;

    f16x8 cb0a = *(const f16x8*)(pv0);
    f16x8 cb0b = *(const f16x8*)(pv0 + 16);
    f16x8 cb1a = *(const f16x8*)(pv1);
    f16x8 cb1b = *(const f16x8*)(pv1 + 16);

    for (int c = 0; c < 32; ++c) {
        // prefetch next chunk's V fragments (c=31 overruns 64B into next ws buffer: valid mem, discarded)
        const __half* nv0 = pv0 + (c + 1) * 32;
        const __half* nv1 = pv1 + (c + 1) * 32;
        f16x8 nb0a = *(const f16x8*)(nv0);
        f16x8 nb0b = *(const f16x8*)(nv0 + 16);
        f16x8 nb1a = *(const f16x8*)(nv1);
        f16x8 nb1b = *(const f16x8*)(nv1 + 16);
        // kap JIT (broadcast 2-line loads)
        const float* kc = kap + c * 32;
        f32x4 k0 = *(const f32x4*)(kc);
        f32x4 k1 = *(const f32x4*)(kc + 4);
        f32x4 k2 = *(const f32x4*)(kc + 16);
        f32x4 k3 = *(const f32x4*)(kc + 20);
        f16x8 ah0, ah1;
#pragma unroll
        for (int e = 0; e < 4; ++e) {
            float p0 = __builtin_amdgcn_exp2f(fmaf(q2, k0[e], -m2));
            float p1 = __builtin_amdgcn_exp2f(fmaf(q2, k1[e], -m2));
            float p2 = __builtin_amdgcn_exp2f(fmaf(q2, k2[e], -m2));
            float p3 = __builtin_amdgcn_exp2f(fmaf(q2, k3[e], -m2));
            den += p0 + p1 + p2 + p3;
            ah0[e] = (_Float16)p0; ah0[e + 4] = (_Float16)p1;
            ah1[e] = (_Float16)p2; ah1[e + 4] = (_Float16)p3;
        }
        acc0 = __builtin_amdgcn_mfma_f32_32x32x16_f16(ah0, cb0a, acc0, 0, 0, 0);
        acc1 = __builtin_amdgcn_mfma_f32_32x32x16_f16(ah0, cb1a, acc1, 0, 0, 0);
        acc0 = __builtin_amdgcn_mfma_f32_32x32x16_f16(ah1, cb0b, acc0, 0, 0, 0);
        acc1 = __builtin_amdgcn_mfma_f32_32x32x16_f16(ah1, cb1b, acc1, 0, 0, 0);
        cb0a = nb0a; cb0b = nb0b; cb1a = nb1a; cb1b = nb1b;
    }

    // combine jseg partials (exact global max -> partials add linearly)
    if (jseg == 1) {
        float* cb = &comb[tile][lane][0];
#pragma unroll
        for (int e = 0; e < 16; ++e) { cb[e] = acc0[e]; cb[e + 16] = acc1[e]; }
        cb[32] = den;
    }
    __syncthreads();
    if (jseg == 0) {
        const float* cb = &comb[tile][lane][0];
#pragma unroll
        for (int e = 0; e < 16; ++e) { acc0[e] += cb[e]; acc1[e] += cb[e + 16]; }
        den += cb[32];
        den += __shfl_xor(den, 32);
        // C layout: col = lane&31, row = (reg&3) + 8*(reg>>2) + 4*kh  (validated r5-r9)
        float* ob = out + (size_t)b * NN * (HH * FF) + (size_t)h * FF;
#pragma unroll
        for (int reg = 0; reg < 16; ++reg) {
            int rloc = (reg & 3) + 8 * (reg >> 2) + 4 * kh;
            float d = __shfl(den, rloc);
            float inv = 1.0f / d;
            int n = rowtile * 32 + rloc;
            float* op = ob + (size_t)n * (HH * FF);
            op[rl]      = acc0[reg] * inv;
            op[32 + rl] = acc1[reg] * inv;
        }
    }
}

extern "C" void kernel_launch(void* const* d_in, const int* in_sizes, int n_in,
                              void* d_out, int out_size, void* d_ws, size_t ws_size,
                              hipStream_t stream) {
    const float* X  = (const float*)d_in[0];
    const float* vW = (const float*)d_in[1];
    const float* vb = (const float*)d_in[2];
    const float* qW = (const float*)d_in[3];
    const float* qb = (const float*)d_in[4];
    const float* kW = (const float*)d_in[5];
    const float* kb = (const float*)d_in[6];
    float* out = (float*)d_out;

    char* w = (char*)d_ws;
    __half* Vt  = (__half*)(w);                   // 1,048,576 B
    float* Qt2  = (float*)(w + 1048576);          // 262,144 B
    float* kapP = (float*)(w + 1310720);          // 262,144 B
    float* kapN = (float*)(w + 1572864);          // 262,144 B
    float* Mpp  = (float*)(w + 1835008);          // 1,024 B
    float* Mnp  = (float*)(w + 1836032);          // 1,024 B

    k_vqk<<<(BB * NN) / 16, 256, 0, stream>>>(X, vW, vb, qW, qb, kW, kb,
                                              Vt, Qt2, kapP, kapN);
    k_m<<<BB * HH * 8, 256, 0, stream>>>(kapP, kapN, Mpp, Mnp);
    k_attn<<<BB * HH * 32, 256, 0, stream>>>(Qt2, kapP, kapN, Mpp, Mnp, Vt, out);
}

// Round 11
// 143.764 us; speedup vs baseline: 2.4276x; 1.2661x over previous
//
#include <hip/hip_runtime.h>
#include <hip/hip_fp16.h>

#define BB 4
#define NN 2048
#define INF 256
#define FF 64
#define HH 8
#define NEG 0.01f
#define LOG2E 1.44269504088896340736f

typedef __attribute__((ext_vector_type(8))) _Float16 f16x8;
typedef __attribute__((ext_vector_type(4))) _Float16 f16x4v;
typedef __attribute__((ext_vector_type(16))) float f32x16;
typedef __attribute__((ext_vector_type(4))) float f32x4;

// ---- K1: fused V + Vt(f16) + Q/K/kap. 512 blocks x 256 thr, 16 rows/block ----
// lane = f (64-wide) so vW loads are 256B contiguous; X rows are wave-uniform -> s_load.
__global__ __launch_bounds__(256) void k_vqk(const float* __restrict__ X,
    const float* __restrict__ vW, const float* __restrict__ vb,
    const float* __restrict__ qW, const float* __restrict__ qb,
    const float* __restrict__ kW, const float* __restrict__ kb,
    __half* __restrict__ Vt,
    float* __restrict__ Qt2, float* __restrict__ kapP, float* __restrict__ kapN)
{
    __shared__ float vstage[16][68];
    __shared__ float qwl[512], kwl[512];   // [f*8+h]
    const int t = threadIdx.x;
    const int n0 = blockIdx.x * 16;      // GLOBAL row base
    const int b = n0 >> 11;
    const int nl = n0 & (NN - 1);        // LOCAL row base (r8 lesson)

    qwl[t] = qW[t]; qwl[t + 256] = qW[t + 256];
    kwl[t] = kW[t]; kwl[t + 256] = kW[t + 256];

    // Phase A: thread (f = t&63, rg = t>>6) computes V[rg*4 + 0..3][f]
    {
        const int f = t & 63, rg = t >> 6;
        const float bias = vb[f];
        float a0 = bias, a1 = bias, a2 = bias, a3 = bias;
        const float* x0 = X + (size_t)(n0 + rg * 4 + 0) * INF;  // wave-uniform -> s_load
        const float* x1 = X + (size_t)(n0 + rg * 4 + 1) * INF;
        const float* x2 = X + (size_t)(n0 + rg * 4 + 2) * INF;
        const float* x3 = X + (size_t)(n0 + rg * 4 + 3) * INF;
        const float* wp = vW + f;
#pragma unroll 8
        for (int k = 0; k < INF; ++k) {
            float w = wp[k * FF];          // lanes contiguous in f -> coalesced
            a0 = fmaf(x0[k], w, a0);
            a1 = fmaf(x1[k], w, a1);
            a2 = fmaf(x2[k], w, a2);
            a3 = fmaf(x3[k], w, a3);
        }
        vstage[rg * 4 + 0][f] = a0;
        vstage[rg * 4 + 1][f] = a1;
        vstage[rg * 4 + 2][f] = a2;
        vstage[rg * 4 + 3][f] = a3;
    }
    __syncthreads();
    // Phase B: Vt f16 transposed write: thread (f2 = t>>2, nq = t&3) -> 4 n each
    {
        const int f2 = t >> 2, nq = t & 3;
        f16x4v hb;
#pragma unroll
        for (int e = 0; e < 4; ++e) hb[e] = (_Float16)vstage[nq * 4 + e][f2];
        *(f16x4v*)(Vt + ((size_t)b * FF + f2) * NN + nl + nq * 4) = hb;
    }
    // Phase C: Q/K: thread (r = t>>4, h = (t>>1)&7, half = t&1): dot-32 + pair-combine
    {
        const int r = t >> 4, h = (t >> 1) & 7, half = t & 1;
        float pq = 0.f, pk = 0.f;
        const int f0 = half * 32;
#pragma unroll
        for (int i = 0; i < 32; ++i) {
            float v = vstage[r][f0 + i];
            pq = fmaf(v, qwl[(f0 + i) * 8 + h], pq);
            pk = fmaf(v, kwl[(f0 + i) * 8 + h], pk);
        }
        float oq = __shfl_xor(pq, 1);
        float ok = __shfl_xor(pk, 1);
        if (half == 0) {
            float qa = pq + oq + qb[h];
            float ka = pk + ok + kb[h];
            size_t o = ((size_t)(b * HH + h)) * NN + nl + r;
            Qt2[o] = qa * LOG2E;
            kapP[o] = fmaxf(ka, NEG * ka);
            kapN[o] = fminf(ka, NEG * ka);
        }
    }
}

// ---- K2: partial Mp/Mn per (bh, 256-j segment): 256 blocks ----
__global__ __launch_bounds__(256) void k_m(const float* __restrict__ kapP,
                                           const float* __restrict__ kapN,
                                           float* __restrict__ Mpp,
                                           float* __restrict__ Mnp) {
    const int bh = blockIdx.x >> 3, seg = blockIdx.x & 7;
    const int tid = threadIdx.x;
    const int j = seg * 256 + tid;
    float mp = kapP[(size_t)bh * NN + j];
    float mn = kapN[(size_t)bh * NN + j];
#pragma unroll
    for (int off = 32; off; off >>= 1) {
        mp = fmaxf(mp, __shfl_down(mp, off));
        mn = fminf(mn, __shfl_down(mn, off));
    }
    __shared__ float sp[4], sn[4];
    if ((tid & 63) == 0) { sp[tid >> 6] = mp; sn[tid >> 6] = mn; }
    __syncthreads();
    if (tid == 0) {
        Mpp[blockIdx.x] = fmaxf(fmaxf(sp[0], sp[1]), fmaxf(sp[2], sp[3]));
        Mnp[blockIdx.x] = fminf(fminf(sn[0], sn[1]), fminf(sn[2], sn[3]));
    }
}

// ---- K3: MFMA fused exp + P@V with LDS-staged, XOR-swizzled V (shared by 4 waves).
// 512 blocks x 4 waves; block = one bh x 128 rows; wave = 32-row tile, full 2048 j.
// Per 128-j chunk: reg-stage 16KB V coalesced (issue-early/write-late), dbuf LDS;
// 8 slices x {2 swizzled ds_read_b128 + 8 exp2 + 2 MFMA}. One barrier per chunk.
#define JC 128                 // j per chunk
#define NCHUNK (NN / JC)       // 16
#define BUFB 16384             // bytes per LDS buffer: 64 f x 128 j x 2B
__global__ __launch_bounds__(256, 2) void k_attn(const float* __restrict__ Qt2,
                                                 const float* __restrict__ kapP,
                                                 const float* __restrict__ kapN,
                                                 const float* __restrict__ Mpp,
                                                 const float* __restrict__ Mnp,
                                                 const __half* __restrict__ Vt,
                                                 float* __restrict__ out) {
    __shared__ __align__(16) char vlds[2 * BUFB];
    const int tid = threadIdx.x;
    const int lane = tid & 63;
    const int wave = tid >> 6;
    const int blk = blockIdx.x;
    const int xcd = blk & 7;            // XCD-grouped: 2 XCDs per b -> Vt[b] L2-resident
    const int sub = blk >> 3;           // 0..63
    const int bh = xcd * 4 + (sub >> 4);
    const int rowblock = sub & 15;
    const int b = bh >> 3, h = bh & 7;

    const int rl = lane & 31;
    const int kh = lane >> 5;
    const int row = rowblock * 128 + wave * 32 + rl;

    // ---- staging identity: instr i of this wave covers f rows [ (wave*4+i)*4 .. +4 )
    const int jp = lane & 15;                 // 16B unit within a 256B f-row
    const __half* srcRow[4];
    int dstOff[4];
#pragma unroll
    for (int i = 0; i < 4; ++i) {
        const int f = (wave * 4 + i) * 4 + (lane >> 4);
        srcRow[i] = Vt + ((size_t)b * FF + f) * NN + jp * 8;
        dstOff[i] = f * 256 + ((jp * 16) ^ ((f & 7) << 4));   // XOR-swizzle (G4)
    }

    const float q2 = Qt2[(size_t)bh * NN + row];
    float mp = Mpp[bh * 8], mn = Mnp[bh * 8];
#pragma unroll
    for (int s = 1; s < 8; ++s) {
        mp = fmaxf(mp, Mpp[bh * 8 + s]);
        mn = fminf(mn, Mnp[bh * 8 + s]);
    }
    const float m2 = (q2 > 0.f) ? q2 * mp : q2 * mn;  // exact row max (log2 units)
    const float* kap = ((q2 > 0.f) ? kapP : kapN) + (size_t)bh * NN + kh * 8;

    // fragment read offsets (swizzled, same XOR as write)
    const int rdBase = rl * 256;
    const int rdSwz = (rl & 7) << 4;
    const int khOff = kh * 16;

    f32x16 acc0 = {}, acc1 = {};
    float den = 0.f;

    // prologue: stage chunk 0
    {
        f16x8 rs[4];
#pragma unroll
        for (int i = 0; i < 4; ++i) rs[i] = *(const f16x8*)(srcRow[i]);
#pragma unroll
        for (int i = 0; i < 4; ++i) *(f16x8*)(vlds + dstOff[i]) = rs[i];
    }

    for (int c = 0; c < NCHUNK; ++c) {
        __syncthreads();                     // buf[c&1] ready; prior reads of buf[(c+1)&1] done
        const char* cbuf = vlds + (c & 1) * BUFB;
        char* nbuf = vlds + ((c + 1) & 1) * BUFB;
        f16x8 rs[4];
        if (c + 1 < NCHUNK) {                // issue-early (T14): loads hide under compute
#pragma unroll
            for (int i = 0; i < 4; ++i)
                rs[i] = *(const f16x8*)(srcRow[i] + (size_t)(c + 1) * JC);
        }
        const float* kapc = kap + c * JC;
#pragma unroll
        for (int s = 0; s < 8; ++s) {
            const int off = rdBase + ((s * 32 + khOff) ^ rdSwz);
            f16x8 cb0 = *(const f16x8*)(cbuf + off);
            f16x8 cb1 = *(const f16x8*)(cbuf + off + 32 * 256);
            f32x4 k0 = *(const f32x4*)(kapc + s * 16);
            f32x4 k1 = *(const f32x4*)(kapc + s * 16 + 4);
            f16x8 ah;
#pragma unroll
            for (int e = 0; e < 4; ++e) {
                float p0 = __builtin_amdgcn_exp2f(fmaf(q2, k0[e], -m2));
                float p1 = __builtin_amdgcn_exp2f(fmaf(q2, k1[e], -m2));
                den += p0 + p1;
                ah[e] = (_Float16)p0;
                ah[e + 4] = (_Float16)p1;
            }
            acc0 = __builtin_amdgcn_mfma_f32_32x32x16_f16(ah, cb0, acc0, 0, 0, 0);
            acc1 = __builtin_amdgcn_mfma_f32_32x32x16_f16(ah, cb1, acc1, 0, 0, 0);
        }
        if (c + 1 < NCHUNK) {                // write-late: lands before next top barrier
#pragma unroll
            for (int i = 0; i < 4; ++i) *(f16x8*)(nbuf + dstOff[i]) = rs[i];
        }
    }

    // epilogue: merge k-halves -> full row denominator, normalize, store
    den += __shfl_xor(den, 32);
    // C layout: col = lane&31, row = (reg&3) + 8*(reg>>2) + 4*kh  (validated r5-r10)
    float* ob = out + (size_t)b * NN * (HH * FF) + (size_t)h * FF;
#pragma unroll
    for (int reg = 0; reg < 16; ++reg) {
        int rloc = (reg & 3) + 8 * (reg >> 2) + 4 * kh;
        float d = __shfl(den, rloc);
        float inv = 1.0f / d;
        int n = rowblock * 128 + wave * 32 + rloc;
        float* op = ob + (size_t)n * (HH * FF);
        op[rl]      = acc0[reg] * inv;
        op[32 + rl] = acc1[reg] * inv;
    }
}

extern "C" void kernel_launch(void* const* d_in, const int* in_sizes, int n_in,
                              void* d_out, int out_size, void* d_ws, size_t ws_size,
                              hipStream_t stream) {
    const float* X  = (const float*)d_in[0];
    const float* vW = (const float*)d_in[1];
    const float* vb = (const float*)d_in[2];
    const float* qW = (const float*)d_in[3];
    const float* qb = (const float*)d_in[4];
    const float* kW = (const float*)d_in[5];
    const float* kb = (const float*)d_in[6];
    float* out = (float*)d_out;

    char* w = (char*)d_ws;
    __half* Vt  = (__half*)(w);                   // 1,048,576 B
    float* Qt2  = (float*)(w + 1048576);          // 262,144 B
    float* kapP = (float*)(w + 1310720);          // 262,144 B
    float* kapN = (float*)(w + 1572864);          // 262,144 B
    float* Mpp  = (float*)(w + 1835008);          // 1,024 B
    float* Mnp  = (float*)(w + 1836032);          // 1,024 B

    k_vqk<<<(BB * NN) / 16, 256, 0, stream>>>(X, vW, vb, qW, qb, kW, kb,
                                              Vt, Qt2, kapP, kapN);
    k_m<<<BB * HH * 8, 256, 0, stream>>>(kapP, kapN, Mpp, Mnp);
    k_attn<<<512, 256, 0, stream>>>(Qt2, kapP, kapN, Mpp, Mnp, Vt, out);
}